// Round 19
// baseline (777.399 us; speedup 1.0000x reference)
//
#include <hip/hip_runtime.h>
#include <hip/hip_bf16.h>

typedef float f32x4 __attribute__((ext_vector_type(4)));
typedef short bf16x8 __attribute__((ext_vector_type(8)));

#define HD 128
#define TILE 16             // edges per block in edge kernel (16 -> ~18KB LDS -> 8 blocks/CU)
#define SCAN_TILE 2048      // counts per scan block (256 thr x 8)

__device__ __forceinline__ float prelu_f(float x, float a) {
  return x > 0.f ? x : a * x;
}

__device__ __forceinline__ unsigned short f2bf(float x) {
  __hip_bfloat16 h = __float2bfloat16(x);
  return *reinterpret_cast<unsigned short*>(&h);
}
__device__ __forceinline__ float bf2f(unsigned short u) {
  union { unsigned u; float f; } a; a.u = ((unsigned)u) << 16;
  return a.f;
}
__device__ __forceinline__ f32x4 bf4_to_f32(ushort4 u) {
  f32x4 r; r[0] = bf2f(u.x); r[1] = bf2f(u.y); r[2] = bf2f(u.z); r[3] = bf2f(u.w);
  return r;
}

// fused: out = concat(ns, nv)  AND  ns_bf/nv_bf = bf16(ns/nv)
__global__ __launch_bounds__(256) void init_conv_kernel(
    const f32x4* __restrict__ ns, const f32x4* __restrict__ nv,
    f32x4* __restrict__ out, ushort4* __restrict__ ns_bf, ushort4* __restrict__ nv_bf,
    int n_ns4, int n_nv4)
{
  int total = n_ns4 + n_nv4;
  for (int i = blockIdx.x * 256 + threadIdx.x; i < total; i += gridDim.x * 256) {
    f32x4 v = (i < n_ns4) ? ns[i] : nv[i - n_ns4];
    out[i] = v;
    ushort4 o;
    o.x = f2bf(v[0]); o.y = f2bf(v[1]); o.z = f2bf(v[2]); o.w = f2bf(v[3]);
    if (i < n_ns4) ns_bf[i] = o; else nv_bf[i - n_ns4] = o;
  }
}

// fused weight prep: 4x w2t[384][128], 2x w1n[128][128], 2x w1e[128][32] (padded)
__global__ __launch_bounds__(256) void weights_prep_kernel(
    const float* __restrict__ w2s_che, const float* __restrict__ w2f_che,
    const float* __restrict__ w2s_vdw, const float* __restrict__ w2f_vdw,
    const float* __restrict__ w1n_che, const float* __restrict__ w1n_vdw,
    const float* __restrict__ w1e_che, const float* __restrict__ w1e_vdw,
    unsigned short* __restrict__ d_w2t_sche, unsigned short* __restrict__ d_w2t_fche,
    unsigned short* __restrict__ d_w2t_svdw, unsigned short* __restrict__ d_w2t_fvdw,
    unsigned short* __restrict__ d_w1t_nche, unsigned short* __restrict__ d_w1t_nvdw,
    unsigned short* __restrict__ d_w1t_eche, unsigned short* __restrict__ d_w1t_evdw)
{
  int idx = blockIdx.x * 256 + threadIdx.x;
  if (idx < 4 * 49152) {
    int which = idx / 49152, rem = idx % 49152;
    int c = rem >> 7, k = rem & 127;
    const float* s = which == 0 ? w2s_che : which == 1 ? w2f_che : which == 2 ? w2s_vdw : w2f_vdw;
    unsigned short* d = which == 0 ? d_w2t_sche : which == 1 ? d_w2t_fche : which == 2 ? d_w2t_svdw : d_w2t_fvdw;
    d[rem] = f2bf(s[(size_t)k * 384 + c]);
  } else if (idx < 4 * 49152 + 2 * 16384) {
    int rem2 = idx - 4 * 49152;
    int which = rem2 / 16384, rem = rem2 % 16384;
    int c = rem >> 7, k = rem & 127;
    const float* s = which ? w1n_vdw : w1n_che;
    unsigned short* d = which ? d_w1t_nvdw : d_w1t_nche;
    d[rem] = f2bf(s[(size_t)k * 128 + c]);
  } else if (idx < 4 * 49152 + 2 * 16384 + 2 * 4096) {
    int rem2 = idx - 4 * 49152 - 2 * 16384;
    int which = rem2 / 4096, rem = rem2 % 4096;
    int c = rem >> 5, k = rem & 31;
    const float* s = which ? w1e_vdw : w1e_che;
    unsigned short* d = which ? d_w1t_evdw : d_w1t_eche;
    d[rem] = (k < 20) ? f2bf(s[(size_t)k * 128 + c]) : (unsigned short)0;
  }
}

// ---------------- node MLP: both layers bf16 MFMA, bf16 output ----------------
__global__ __launch_bounds__(256) void node_mlp_mfma(
    const unsigned short* __restrict__ Abf,  // [M,128] bf16
    const unsigned short* __restrict__ w1t,  // [128][128] bf16
    const float* __restrict__ b1, const float* __restrict__ a1p,
    const unsigned short* __restrict__ w2t,  // [384][128] bf16
    const float* __restrict__ b2, const float* __restrict__ a2p,
    unsigned short* __restrict__ out,        // [M,384] bf16
    int M)
{
  __shared__ __attribute__((aligned(16))) unsigned short A_lds[64 * HD];
  __shared__ __attribute__((aligned(16))) unsigned short h_lds[64 * HD];
  const int t = threadIdx.x;
  const int wvid = t >> 6, lane = t & 63, l15 = lane & 15, l4 = lane >> 4;
  const int m0 = blockIdx.x * 64;
  const float a1 = a1p[0], a2 = a2p[0];

  for (int idx = t; idx < 64 * HD / 8; idx += 256) {
    int row = idx >> 4, seg = (idx & 15) * 8;
    bf16x8 v = 0;
    if (m0 + row < M) v = *(const bf16x8*)&Abf[(size_t)(m0 + row) * HD + seg];
    *(bf16x8*)&A_lds[row * HD + (seg ^ ((row & 7) << 3))] = v;
  }
  __syncthreads();

  // layer1 MFMA (K=128) -> h bf16 swizzled
  {
    bf16x8 Bf[2][4];
    #pragma unroll
    for (int nf = 0; nf < 2; nf++)
      #pragma unroll
      for (int ks = 0; ks < 4; ks++) {
        int col = wvid * 32 + nf * 16 + l15;
        Bf[nf][ks] = *(const bf16x8*)&w1t[(size_t)col * 128 + ks * 32 + l4 * 8];
      }
    f32x4 D[4][2];
    #pragma unroll
    for (int mi = 0; mi < 4; mi++)
      #pragma unroll
      for (int nf = 0; nf < 2; nf++)
        #pragma unroll
        for (int cc = 0; cc < 4; cc++) D[mi][nf][cc] = 0.f;

    #pragma unroll
    for (int mi = 0; mi < 4; mi++)
      #pragma unroll
      for (int ks = 0; ks < 4; ks++) {
        int row = mi * 16 + l15;
        bf16x8 Af = *(const bf16x8*)&A_lds[row * HD + ((ks * 32 + l4 * 8) ^ ((row & 7) << 3))];
        D[mi][0] = __builtin_amdgcn_mfma_f32_16x16x32_bf16(Af, Bf[0][ks], D[mi][0], 0, 0, 0);
        D[mi][1] = __builtin_amdgcn_mfma_f32_16x16x32_bf16(Af, Bf[1][ks], D[mi][1], 0, 0, 0);
      }

    float b1v0 = b1[wvid * 32 + l15];
    float b1v1 = b1[wvid * 32 + 16 + l15];
    #pragma unroll
    for (int mi = 0; mi < 4; mi++)
      #pragma unroll
      for (int nf = 0; nf < 2; nf++)
        #pragma unroll
        for (int r4 = 0; r4 < 4; r4++) {
          int row = mi * 16 + l4 * 4 + r4;
          int col = wvid * 32 + nf * 16 + l15;
          h_lds[row * HD + (col ^ ((row & 7) << 3))] =
              f2bf(prelu_f(D[mi][nf][r4] + (nf ? b1v1 : b1v0), a1));
        }
  }
  __syncthreads();

  // layer2 MFMA: 3 plane groups of 128 cols
  for (int m = 0; m < 3; m++) {
    bf16x8 Bf[2][4];
    #pragma unroll
    for (int nf = 0; nf < 2; nf++)
      #pragma unroll
      for (int ks = 0; ks < 4; ks++) {
        int col = m * 128 + wvid * 32 + nf * 16 + l15;
        Bf[nf][ks] = *(const bf16x8*)&w2t[(size_t)col * 128 + ks * 32 + l4 * 8];
      }
    f32x4 D[4][2];
    #pragma unroll
    for (int mi = 0; mi < 4; mi++)
      #pragma unroll
      for (int nf = 0; nf < 2; nf++)
        #pragma unroll
        for (int cc = 0; cc < 4; cc++) D[mi][nf][cc] = 0.f;

    #pragma unroll
    for (int mi = 0; mi < 4; mi++)
      #pragma unroll
      for (int ks = 0; ks < 4; ks++) {
        int row = mi * 16 + l15;
        bf16x8 Af = *(const bf16x8*)&h_lds[row * HD + ((ks * 32 + l4 * 8) ^ ((row & 7) << 3))];
        D[mi][0] = __builtin_amdgcn_mfma_f32_16x16x32_bf16(Af, Bf[0][ks], D[mi][0], 0, 0, 0);
        D[mi][1] = __builtin_amdgcn_mfma_f32_16x16x32_bf16(Af, Bf[1][ks], D[mi][1], 0, 0, 0);
      }

    float b2v0 = b2[m * 128 + wvid * 32 + l15];
    float b2v1 = b2[m * 128 + wvid * 32 + 16 + l15];
    #pragma unroll
    for (int mi = 0; mi < 4; mi++)
      #pragma unroll
      for (int nf = 0; nf < 2; nf++)
        #pragma unroll
        for (int r4 = 0; r4 < 4; r4++) {
          int row = mi * 16 + l4 * 4 + r4;
          if (m0 + row < M) {
            int col = m * 128 + wvid * 32 + nf * 16 + l15;
            out[(size_t)(m0 + row) * 384 + col] =
                f2bf(prelu_f(D[mi][nf][r4] + (nf ? b2v1 : b2v0), a2));
          }
        }
  }
}

// ---------------- CSR build (dual-branch fused) ----------------
__global__ __launch_bounds__(256) void zero_int_kernel(int* __restrict__ p, int n) {
  int i = blockIdx.x * 256 + threadIdx.x;
  if (i < n) p[i] = 0;
}

__global__ __launch_bounds__(256) void hist2_kernel(
    const int* __restrict__ edge_che, const int* __restrict__ edge_vdw,
    int* __restrict__ counts, int N, int E_che, int E_vdw)
{
  int g = blockIdx.x * 256 + threadIdx.x;
  if (g < E_che) {
    atomicAdd(&counts[edge_che[(size_t)g * 2]], 1);
  } else {
    int e2 = g - E_che;
    if (e2 < E_vdw) atomicAdd(&counts[N + edge_vdw[(size_t)e2 * 2]], 1);
  }
}

__global__ __launch_bounds__(256) void scan_partial2_kernel(
    const int* __restrict__ counts, int* __restrict__ partials, int n, int nb)
{
  const int b = blockIdx.x, t = threadIdx.x;
  const int br = b >= nb, lb = b - br * nb;
  const int* cnt = counts + (size_t)br * n;
  const int base = lb * SCAN_TILE + t * 8;
  int s = 0;
  #pragma unroll
  for (int i = 0; i < 8; i++) {
    int idx = base + i;
    if (idx < n) s += cnt[idx];
  }
  __shared__ int sums[256];
  sums[t] = s;
  __syncthreads();
  for (int o = 128; o > 0; o >>= 1) {
    if (t < o) sums[t] += sums[t + o];
    __syncthreads();
  }
  if (t == 0) partials[b] = sums[0];
}

__global__ __launch_bounds__(256) void scan_partials2_kernel(int* __restrict__ partials_g, int nb)
{
  int* partials = partials_g + blockIdx.x * nb;
  __shared__ int s[256];
  const int t = threadIdx.x;
  s[t] = (t < nb) ? partials[t] : 0;
  __syncthreads();
  for (int o = 1; o < 256; o <<= 1) {
    int v = s[t];
    int u = (t >= o) ? s[t - o] : 0;
    __syncthreads();
    s[t] = v + u;
    __syncthreads();
  }
  if (t < nb) partials[t] = (t == 0) ? 0 : s[t - 1];
}

__global__ __launch_bounds__(256) void scan_write2_kernel(
    const int* __restrict__ counts, const int* __restrict__ partials,
    int* __restrict__ offsets, int* __restrict__ cursor, int n, int nb,
    int E_che, int E_vdw)
{
  const int b = blockIdx.x, t = threadIdx.x;
  const int br = b >= nb, lb = b - br * nb;
  const int* cnt = counts + (size_t)br * n;
  int* offs = offsets + (size_t)br * (n + 1);
  int* curs = cursor + (size_t)br * n;
  const int base = lb * SCAN_TILE + t * 8;
  int vals[8];
  int s = 0;
  #pragma unroll
  for (int i = 0; i < 8; i++) {
    int idx = base + i;
    vals[i] = (idx < n) ? cnt[idx] : 0;
    s += vals[i];
  }
  __shared__ int sums[256];
  sums[t] = s;
  __syncthreads();
  for (int o = 1; o < 256; o <<= 1) {
    int v = sums[t];
    int u = (t >= o) ? sums[t - o] : 0;
    __syncthreads();
    sums[t] = v + u;
    __syncthreads();
  }
  int run = partials[b] + ((t == 0) ? 0 : sums[t - 1]);
  #pragma unroll
  for (int i = 0; i < 8; i++) {
    int idx = base + i;
    if (idx < n) {
      offs[idx] = run;
      curs[idx] = run;
      run += vals[i];
    }
  }
  if (lb == 0 && t == 0) offs[n] = br ? E_vdw : E_che;
}

__global__ __launch_bounds__(256) void scatter_ids2_kernel(
    const int* __restrict__ edge_che, const int* __restrict__ edge_vdw,
    int* __restrict__ cursor, int* __restrict__ edge_list,
    int N, int E_che, int E_vdw)
{
  int g = blockIdx.x * 256 + threadIdx.x;
  if (g < E_che) {
    int d = edge_che[(size_t)g * 2];
    int p = atomicAdd(&cursor[d], 1);
    edge_list[p] = g;
  } else {
    int e2 = g - E_che;
    if (e2 < E_vdw) {
      int d = edge_vdw[(size_t)e2 * 2];
      int p = atomicAdd(&cursor[N + d], 1);
      edge_list[E_che + p] = e2;
    }
  }
}

// permute edge data into CSR (dst-sorted) order, both branches, concatenated
__global__ __launch_bounds__(256) void permute2_kernel(
    const int* __restrict__ edge_list,
    const int* __restrict__ edge_che, const float* __restrict__ diff_che,
    const float* __restrict__ dist_che, const float* __restrict__ rbf_che,
    const int* __restrict__ edge_vdw, const float* __restrict__ diff_vdw,
    const float* __restrict__ dist_vdw, const float* __restrict__ rbf_vdw,
    int* __restrict__ src_s, int* __restrict__ dst_s,
    float4* __restrict__ unit_s, unsigned short* __restrict__ rbf_b,
    int E_che, int E_vdw)
{
  int p = blockIdx.x * 256 + threadIdx.x;
  if (p >= E_che + E_vdw) return;
  int br = p >= E_che;
  int e = edge_list[p];
  const int* edge = br ? edge_vdw : edge_che;
  const float* diff = br ? diff_vdw : diff_che;
  const float* dist = br ? dist_vdw : dist_che;
  const float* rbf  = br ? rbf_vdw  : rbf_che;
  src_s[p] = edge[(size_t)e * 2 + 1];
  dst_s[p] = edge[(size_t)e * 2 + 0];
  float inv = 1.f / dist[e];
  float4 u;
  u.x = diff[(size_t)e * 3 + 0] * inv;
  u.y = diff[(size_t)e * 3 + 1] * inv;
  u.z = diff[(size_t)e * 3 + 2] * inv;
  u.w = 0.f;
  unit_s[p] = u;
  ushort4* ro = (ushort4*)(rbf_b + (size_t)p * 32);
  const float* rr = &rbf[(size_t)e * 20];
  #pragma unroll
  for (int i = 0; i < 5; i++) {
    ushort4 o;
    o.x = f2bf(rr[4 * i + 0]); o.y = f2bf(rr[4 * i + 1]);
    o.z = f2bf(rr[4 * i + 2]); o.w = f2bf(rr[4 * i + 3]);
    ro[i] = o;
  }
  ushort4 z; z.x = 0; z.y = 0; z.z = 0; z.w = 0;
  ro[5] = z; ro[6] = z; ro[7] = z;
}

// ---------------- fused edge kernel (TILE=16): filter MLP (both layers MFMA) +
// bf16 gather + gate + in-LDS segmented reduction + direct RMW / boundary atomics ----------------
__global__ __launch_bounds__(256, 4) void edge_mfma_reduce_kernel(
    const unsigned short* __restrict__ so,  // [N,384] bf16
    const unsigned short* __restrict__ nv,  // [N,3,128] bf16
    const int*   __restrict__ src_s,   // [E] sorted
    const int*   __restrict__ dst_s,   // [E] sorted
    const float4* __restrict__ unit_s, // [E] sorted
    const unsigned short* __restrict__ rbf_b, // [E*32] sorted bf16 K-padded
    const int*   __restrict__ offsets, // [N+1] (branch's)
    const unsigned short* __restrict__ w1t, // [128][32] bf16
    const float* __restrict__ b1, const float* __restrict__ a1p,
    const unsigned short* __restrict__ w2t, // [384][128] bf16
    const float* __restrict__ b2, const float* __restrict__ a2p,
    float* __restrict__ out,           // [N,128]+[N,3,128] residual-initialized
    int N, int E)
{
  __shared__ __attribute__((aligned(16))) unsigned short A1_lds[TILE * 40]; // stride-40 pad
  __shared__ __attribute__((aligned(16))) unsigned short h_lds[TILE * HD];
  __shared__ __attribute__((aligned(16))) unsigned short P_lds[3][TILE * HD];
  __shared__ int src_l[TILE];
  __shared__ float unit_l[TILE][3];
  __shared__ int run_rs[TILE + 1], run_node[TILE], run_flag[TILE];
  __shared__ int nd_s;

  const int t = threadIdx.x;
  const int tx = t & 31, ty = t >> 5;
  const int c4 = tx * 4;
  const int wvid = t >> 6, lane = t & 63, l15 = lane & 15, l4 = lane >> 4;
  const int pblk = blockIdx.x * TILE;
  const int nrows = min(TILE, E - pblk);
  const float a1 = a1p[0], a2 = a2p[0];

  // wave0: meta staging + run detection (register-based, no LDS RAW)
  if (t < 64) {
    int d = -1, s = 0;
    float ux = 0.f, uy = 0.f, uz = 0.f;
    if (t < nrows) {
      s = src_s[pblk + t];
      d = dst_s[pblk + t];
      float4 u = unit_s[pblk + t];
      ux = u.x; uy = u.y; uz = u.z;
    }
    if (t < TILE) {
      src_l[t] = s;
      unit_l[t][0] = ux; unit_l[t][1] = uy; unit_l[t][2] = uz;
    }
    int dprev = __shfl_up(d, 1);
    bool flag = (t < nrows) && (t == 0 || d != dprev);
    unsigned long long mask = __ballot(flag ? 1 : 0);
    if (flag) {
      int j = __popcll(mask & ((1ull << t) - 1ull));
      run_rs[j] = t;
      run_node[j] = d;
      unsigned long long rest = (t == 63) ? 0ull : (mask >> (t + 1));
      int re = rest ? (t + 1 + (__ffsll((long long)rest) - 1)) : nrows;
      int interior = 1;
      if (t == 0 && offsets[d] != pblk) interior = 0;
      if (re == nrows && offsets[d + 1] != pblk + nrows) interior = 0;
      run_flag[j] = interior;
    }
    if (t == 0) {
      int nd = __popcll(mask);
      nd_s = nd;
      run_rs[nd] = nrows;
    }
  }

  // A1 staging: TILE rows x 32 bf16 (contiguous, coalesced), padded LDS stride 40
  if (t < TILE * 4) {
    const bf16x8* rb = (const bf16x8*)(rbf_b + (size_t)pblk * 32);
    int row = t >> 2, seg = (t & 3) * 8;
    *(bf16x8*)&A1_lds[row * 40 + seg] = rb[t];
  }
  __syncthreads();   // S1

  // layer1 MFMA (K=32), rows 0..15 -> h bf16 swizzled
  {
    bf16x8 B1[2];
    B1[0] = *(const bf16x8*)&w1t[(size_t)(wvid * 32 + l15) * 32 + l4 * 8];
    B1[1] = *(const bf16x8*)&w1t[(size_t)(wvid * 32 + 16 + l15) * 32 + l4 * 8];
    f32x4 D1[2];
    #pragma unroll
    for (int nf = 0; nf < 2; nf++)
      #pragma unroll
      for (int cc = 0; cc < 4; cc++) D1[nf][cc] = 0.f;

    {
      bf16x8 Af = *(const bf16x8*)&A1_lds[l15 * 40 + l4 * 8];
      D1[0] = __builtin_amdgcn_mfma_f32_16x16x32_bf16(Af, B1[0], D1[0], 0, 0, 0);
      D1[1] = __builtin_amdgcn_mfma_f32_16x16x32_bf16(Af, B1[1], D1[1], 0, 0, 0);
    }

    float b1v0 = b1[wvid * 32 + l15];
    float b1v1 = b1[wvid * 32 + 16 + l15];
    #pragma unroll
    for (int nf = 0; nf < 2; nf++)
      #pragma unroll
      for (int r4 = 0; r4 < 4; r4++) {
        int row = l4 * 4 + r4;
        int col = wvid * 32 + nf * 16 + l15;
        h_lds[row * HD + (col ^ ((row & 7) << 3))] =
            f2bf(prelu_f(D1[nf][r4] + (nf ? b1v1 : b1v0), a1));
      }
  }
  __syncthreads();   // S2

  // layer2 MFMA: 3 planes, rows 0..15 -> P_lds (gv, ms, ge gates)
  for (int m = 0; m < 3; m++) {
    bf16x8 Bf[2][4];
    #pragma unroll
    for (int nf = 0; nf < 2; nf++)
      #pragma unroll
      for (int ks = 0; ks < 4; ks++) {
        int col = m * 128 + wvid * 32 + nf * 16 + l15;
        Bf[nf][ks] = *(const bf16x8*)&w2t[(size_t)col * 128 + ks * 32 + l4 * 8];
      }
    f32x4 D[2];
    #pragma unroll
    for (int nf = 0; nf < 2; nf++)
      #pragma unroll
      for (int cc = 0; cc < 4; cc++) D[nf][cc] = 0.f;

    #pragma unroll
    for (int ks = 0; ks < 4; ks++) {
      int row = l15;
      bf16x8 Af = *(const bf16x8*)&h_lds[row * HD + ((ks * 32 + l4 * 8) ^ ((row & 7) << 3))];
      D[0] = __builtin_amdgcn_mfma_f32_16x16x32_bf16(Af, Bf[0][ks], D[0], 0, 0, 0);
      D[1] = __builtin_amdgcn_mfma_f32_16x16x32_bf16(Af, Bf[1][ks], D[1], 0, 0, 0);
    }

    float b2v0 = b2[m * 128 + wvid * 32 + l15];
    float b2v1 = b2[m * 128 + wvid * 32 + 16 + l15];
    #pragma unroll
    for (int nf = 0; nf < 2; nf++)
      #pragma unroll
      for (int r4 = 0; r4 < 4; r4++) {
        int row = l4 * 4 + r4;
        int col = wvid * 32 + nf * 16 + l15;
        float v = prelu_f(D[nf][r4] + (nf ? b2v1 : b2v0), a2);
        P_lds[m][row * HD + (col ^ ((row & 7) << 3))] = f2bf(v);
      }
  }
  __syncthreads();   // S3

  // epilogue A (owner phase): gather + gate; overwrite LDS planes in place with
  // final messages: ms -> h_lds, mv0/1/2 -> P_lds[0/1/2]. Per-cell exclusive.
  #pragma unroll
  for (int rr = 0; rr < 2; rr++) {
    const int r = ty * 2 + rr;
    const int src = src_l[r];
    const int sc = c4 ^ ((r & 7) << 3);
    f32x4 gvp = bf4_to_f32(*(const ushort4*)&P_lds[0][r * HD + sc]);
    f32x4 msp = bf4_to_f32(*(const ushort4*)&P_lds[1][r * HD + sc]);
    f32x4 gep = bf4_to_f32(*(const ushort4*)&P_lds[2][r * HD + sc]);
    const size_t sb = (size_t)src * 384;
    f32x4 s0 = bf4_to_f32(*(const ushort4*)&so[sb + c4]);
    f32x4 s1 = bf4_to_f32(*(const ushort4*)&so[sb + HD + c4]);
    f32x4 s2 = bf4_to_f32(*(const ushort4*)&so[sb + 2 * HD + c4]);
    f32x4 v0 = bf4_to_f32(*(const ushort4*)&nv[sb + c4]);
    f32x4 v1 = bf4_to_f32(*(const ushort4*)&nv[sb + HD + c4]);
    f32x4 v2 = bf4_to_f32(*(const ushort4*)&nv[sb + 2 * HD + c4]);
    const float u0 = unit_l[r][0], u1 = unit_l[r][1], u2 = unit_l[r][2];
    ushort4 msw, m0w, m1w, m2w;
    #pragma unroll
    for (int cc = 0; cc < 4; cc++) {
      float gv = gvp[cc] * s0[cc];
      float ms = msp[cc] * s1[cc];
      float ge = gep[cc] * s2[cc];
      float mv0 = v0[cc] * gv + u0 * ge;
      float mv1 = v1[cc] * gv + u1 * ge;
      float mv2 = v2[cc] * gv + u2 * ge;
      ((unsigned short*)&msw)[cc] = f2bf(ms);
      ((unsigned short*)&m0w)[cc] = f2bf(mv0);
      ((unsigned short*)&m1w)[cc] = f2bf(mv1);
      ((unsigned short*)&m2w)[cc] = f2bf(mv2);
    }
    *(ushort4*)&h_lds[r * HD + sc]    = msw;
    *(ushort4*)&P_lds[0][r * HD + sc] = m0w;
    *(ushort4*)&P_lds[1][r * HD + sc] = m1w;
    *(ushort4*)&P_lds[2][r * HD + sc] = m2w;
  }
  __syncthreads();   // S4

  // epilogue B (reduction phase): thread t owns 2 cols of one of 4 planes;
  // segment-sum over dst runs; interior -> plain f32x2 RMW, boundary -> atomics.
  {
    const int pl = t >> 6;            // 0: ms, 1..3: mv0..2
    const int c2 = (t & 63) * 2;
    const unsigned short* region = (pl == 0) ? h_lds : &P_lds[pl - 1][0];
    float* out_v = out + (size_t)N * HD;
    const int nd = nd_s;
    for (int j = 0; j < nd; j++) {
      const int rs = run_rs[j], re = run_rs[j + 1];
      const int n = run_node[j];
      float a0 = 0.f, a1v = 0.f;
      for (int r = rs; r < re; r++) {
        int ad = r * HD + (((c2 & ~3) ^ ((r & 7) << 3)) | (c2 & 3));
        unsigned int u = *(const unsigned int*)&region[ad];
        a0  += bf2f((unsigned short)(u & 0xffffu));
        a1v += bf2f((unsigned short)(u >> 16));
      }
      float* dstp = (pl == 0) ? (out + (size_t)n * HD + c2)
                              : (out_v + (size_t)n * 384 + (size_t)(pl - 1) * HD + c2);
      if (run_flag[j]) {
        float2 cur = *(float2*)dstp;
        cur.x += a0; cur.y += a1v;
        *(float2*)dstp = cur;
      } else {
        atomicAdd(dstp, a0);
        atomicAdd(dstp + 1, a1v);
      }
    }
  }
}

extern "C" void kernel_launch(void* const* d_in, const int* in_sizes, int n_in,
                              void* d_out, int out_size, void* d_ws, size_t ws_size,
                              hipStream_t stream)
{
  const float* node_scalar = (const float*)d_in[0];
  const float* node_vector = (const float*)d_in[1];
  const int*   che_edge = (const int*)d_in[2];
  const float* che_diff = (const float*)d_in[3];
  const float* che_dist = (const float*)d_in[4];
  const float* che_rbf  = (const float*)d_in[5];
  const int*   vdw_edge = (const int*)d_in[6];
  const float* vdw_diff = (const float*)d_in[7];
  const float* vdw_dist = (const float*)d_in[8];
  const float* vdw_rbf  = (const float*)d_in[9];
  const float* mlp_p[24];
  for (int i = 0; i < 24; i++) mlp_p[i] = (const float*)d_in[10 + i];
  // [che_s 0..5][che_f 6..11][vdw_s 12..17][vdw_f 18..23]

  const int N = in_sizes[0] / HD;
  const int E_che = in_sizes[4];
  const int E_vdw = in_sizes[8];
  const int E_sum = E_che + E_vdw;
  const int nb_scan = (N + SCAN_TILE - 1) / SCAN_TILE;

  // workspace layout
  char* wp = (char*)d_ws;
  size_t off = 0;
  unsigned short* so_bf = (unsigned short*)(wp + off); off += (size_t)N * 384 * 2;
  unsigned short* nv_bf = (unsigned short*)(wp + off); off += (size_t)N * 384 * 2;
  unsigned short* ns_bf = (unsigned short*)(wp + off); off += (size_t)N * 128 * 2;
  int* counts     = (int*)(wp + off);   off += (size_t)2 * N * 4;
  int* cursor     = (int*)(wp + off);   off += (size_t)2 * N * 4;
  int* offsets    = (int*)(wp + off);   off += (size_t)2 * (N + 1) * 4;
  int* partials   = (int*)(wp + off);   off += 512 * 4;
  off = (off + 255) & ~(size_t)255;
  int* edge_list  = (int*)(wp + off);   off += (size_t)E_sum * 4;
  int* src_s      = (int*)(wp + off);   off += (size_t)E_sum * 4;
  int* dst_s      = (int*)(wp + off);   off += (size_t)E_sum * 4;
  off = (off + 255) & ~(size_t)255;
  float4* unit_s  = (float4*)(wp + off); off += (size_t)E_sum * 16;
  unsigned short* rbf_b = (unsigned short*)(wp + off); off += (size_t)E_sum * 64;
  off = (off + 255) & ~(size_t)255;
  unsigned short* w2t_sche = (unsigned short*)(wp + off); off += 384 * 128 * 2;
  unsigned short* w2t_fche = (unsigned short*)(wp + off); off += 384 * 128 * 2;
  unsigned short* w2t_svdw = (unsigned short*)(wp + off); off += 384 * 128 * 2;
  unsigned short* w2t_fvdw = (unsigned short*)(wp + off); off += 384 * 128 * 2;
  unsigned short* w1t_nche = (unsigned short*)(wp + off); off += 128 * 128 * 2;
  unsigned short* w1t_nvdw = (unsigned short*)(wp + off); off += 128 * 128 * 2;
  unsigned short* w1t_eche = (unsigned short*)(wp + off); off += 128 * 32 * 2;
  unsigned short* w1t_evdw = (unsigned short*)(wp + off); off += 128 * 32 * 2;

  const int n_ns4 = N * HD / 4;
  const int n_nv4 = N * 3 * HD / 4;
  init_conv_kernel<<<2048, 256, 0, stream>>>(
      (const f32x4*)node_scalar, (const f32x4*)node_vector, (f32x4*)d_out,
      (ushort4*)ns_bf, (ushort4*)nv_bf, n_ns4, n_nv4);

  weights_prep_kernel<<<928, 256, 0, stream>>>(
      mlp_p[3], mlp_p[9], mlp_p[15], mlp_p[21],
      mlp_p[0], mlp_p[12], mlp_p[6], mlp_p[18],
      w2t_sche, w2t_fche, w2t_svdw, w2t_fvdw,
      w1t_nche, w1t_nvdw, w1t_eche, w1t_evdw);

  // dual-branch CSR build
  zero_int_kernel<<<(2 * N + 255) / 256, 256, 0, stream>>>(counts, 2 * N);
  hist2_kernel<<<(E_sum + 255) / 256, 256, 0, stream>>>(
      che_edge, vdw_edge, counts, N, E_che, E_vdw);
  scan_partial2_kernel<<<2 * nb_scan, 256, 0, stream>>>(counts, partials, N, nb_scan);
  scan_partials2_kernel<<<2, 256, 0, stream>>>(partials, nb_scan);
  scan_write2_kernel<<<2 * nb_scan, 256, 0, stream>>>(
      counts, partials, offsets, cursor, N, nb_scan, E_che, E_vdw);
  scatter_ids2_kernel<<<(E_sum + 255) / 256, 256, 0, stream>>>(
      che_edge, vdw_edge, cursor, edge_list, N, E_che, E_vdw);
  permute2_kernel<<<(E_sum + 255) / 256, 256, 0, stream>>>(
      edge_list,
      che_edge, che_diff, che_dist, che_rbf,
      vdw_edge, vdw_diff, vdw_dist, vdw_rbf,
      src_s, dst_s, unit_s, rbf_b, E_che, E_vdw);

  for (int br = 0; br < 2; br++) {
    const int E = br == 0 ? E_che : E_vdw;
    const int base = br == 0 ? 0 : E_che;
    const float* const* sp = &mlp_p[br == 0 ? 0 : 12];
    const float* const* fp = &mlp_p[br == 0 ? 6 : 18];
    const unsigned short* w2t_s = br == 0 ? w2t_sche : w2t_svdw;
    const unsigned short* w2t_f = br == 0 ? w2t_fche : w2t_fvdw;
    const unsigned short* w1t_n = br == 0 ? w1t_nche : w1t_nvdw;
    const unsigned short* w1t_e = br == 0 ? w1t_eche : w1t_evdw;

    node_mlp_mfma<<<(N + 63) / 64, 256, 0, stream>>>(
        ns_bf, w1t_n, sp[1], sp[2], w2t_s, sp[4], sp[5], so_bf, N);

    edge_mfma_reduce_kernel<<<(E + TILE - 1) / TILE, 256, 0, stream>>>(
        so_bf, nv_bf,
        src_s + base, dst_s + base, unit_s + base, rbf_b + (size_t)base * 32,
        offsets + (size_t)br * (N + 1),
        w1t_e, fp[1], fp[2], w2t_f, fp[4], fp[5],
        (float*)d_out, N, E);
  }
}

// Round 20
// 627.048 us; speedup vs baseline: 1.2398x; 1.2398x over previous
//
#include <hip/hip_runtime.h>
#include <hip/hip_bf16.h>

typedef float f32x4 __attribute__((ext_vector_type(4)));
typedef short bf16x8 __attribute__((ext_vector_type(8)));

#define HD 128
#define TILE 32             // edges per block in edge kernel (measured optimum)
#define SCAN_TILE 2048      // counts per scan block (256 thr x 8)

__device__ __forceinline__ float prelu_f(float x, float a) {
  return x > 0.f ? x : a * x;
}

__device__ __forceinline__ unsigned short f2bf(float x) {
  __hip_bfloat16 h = __float2bfloat16(x);
  return *reinterpret_cast<unsigned short*>(&h);
}
__device__ __forceinline__ float bf2f(unsigned short u) {
  union { unsigned u; float f; } a; a.u = ((unsigned)u) << 16;
  return a.f;
}
__device__ __forceinline__ f32x4 bf4_to_f32(ushort4 u) {
  f32x4 r; r[0] = bf2f(u.x); r[1] = bf2f(u.y); r[2] = bf2f(u.z); r[3] = bf2f(u.w);
  return r;
}

// fused: out = concat(ns, nv)  AND  ns_bf/nv_bf = bf16(ns/nv)
__global__ __launch_bounds__(256) void init_conv_kernel(
    const f32x4* __restrict__ ns, const f32x4* __restrict__ nv,
    f32x4* __restrict__ out, ushort4* __restrict__ ns_bf, ushort4* __restrict__ nv_bf,
    int n_ns4, int n_nv4)
{
  int total = n_ns4 + n_nv4;
  for (int i = blockIdx.x * 256 + threadIdx.x; i < total; i += gridDim.x * 256) {
    f32x4 v = (i < n_ns4) ? ns[i] : nv[i - n_ns4];
    out[i] = v;
    ushort4 o;
    o.x = f2bf(v[0]); o.y = f2bf(v[1]); o.z = f2bf(v[2]); o.w = f2bf(v[3]);
    if (i < n_ns4) ns_bf[i] = o; else nv_bf[i - n_ns4] = o;
  }
}

// fused weight prep: 4x w2t[384][128], 2x w1n[128][128], 2x w1e[128][32] (padded)
__global__ __launch_bounds__(256) void weights_prep_kernel(
    const float* __restrict__ w2s_che, const float* __restrict__ w2f_che,
    const float* __restrict__ w2s_vdw, const float* __restrict__ w2f_vdw,
    const float* __restrict__ w1n_che, const float* __restrict__ w1n_vdw,
    const float* __restrict__ w1e_che, const float* __restrict__ w1e_vdw,
    unsigned short* __restrict__ d_w2t_sche, unsigned short* __restrict__ d_w2t_fche,
    unsigned short* __restrict__ d_w2t_svdw, unsigned short* __restrict__ d_w2t_fvdw,
    unsigned short* __restrict__ d_w1t_nche, unsigned short* __restrict__ d_w1t_nvdw,
    unsigned short* __restrict__ d_w1t_eche, unsigned short* __restrict__ d_w1t_evdw)
{
  int idx = blockIdx.x * 256 + threadIdx.x;
  if (idx < 4 * 49152) {
    int which = idx / 49152, rem = idx % 49152;
    int c = rem >> 7, k = rem & 127;
    const float* s = which == 0 ? w2s_che : which == 1 ? w2f_che : which == 2 ? w2s_vdw : w2f_vdw;
    unsigned short* d = which == 0 ? d_w2t_sche : which == 1 ? d_w2t_fche : which == 2 ? d_w2t_svdw : d_w2t_fvdw;
    d[rem] = f2bf(s[(size_t)k * 384 + c]);
  } else if (idx < 4 * 49152 + 2 * 16384) {
    int rem2 = idx - 4 * 49152;
    int which = rem2 / 16384, rem = rem2 % 16384;
    int c = rem >> 7, k = rem & 127;
    const float* s = which ? w1n_vdw : w1n_che;
    unsigned short* d = which ? d_w1t_nvdw : d_w1t_nche;
    d[rem] = f2bf(s[(size_t)k * 128 + c]);
  } else if (idx < 4 * 49152 + 2 * 16384 + 2 * 4096) {
    int rem2 = idx - 4 * 49152 - 2 * 16384;
    int which = rem2 / 4096, rem = rem2 % 4096;
    int c = rem >> 5, k = rem & 31;
    const float* s = which ? w1e_vdw : w1e_che;
    unsigned short* d = which ? d_w1t_evdw : d_w1t_eche;
    d[rem] = (k < 20) ? f2bf(s[(size_t)k * 128 + c]) : (unsigned short)0;
  }
}

// ---------------- node MLP: both layers bf16 MFMA, bf16 output ----------------
__global__ __launch_bounds__(256) void node_mlp_mfma(
    const unsigned short* __restrict__ Abf,  // [M,128] bf16
    const unsigned short* __restrict__ w1t,  // [128][128] bf16
    const float* __restrict__ b1, const float* __restrict__ a1p,
    const unsigned short* __restrict__ w2t,  // [384][128] bf16
    const float* __restrict__ b2, const float* __restrict__ a2p,
    unsigned short* __restrict__ out,        // [M,384] bf16
    int M)
{
  __shared__ __attribute__((aligned(16))) unsigned short A_lds[64 * HD];
  __shared__ __attribute__((aligned(16))) unsigned short h_lds[64 * HD];
  const int t = threadIdx.x;
  const int wvid = t >> 6, lane = t & 63, l15 = lane & 15, l4 = lane >> 4;
  const int m0 = blockIdx.x * 64;
  const float a1 = a1p[0], a2 = a2p[0];

  for (int idx = t; idx < 64 * HD / 8; idx += 256) {
    int row = idx >> 4, seg = (idx & 15) * 8;
    bf16x8 v = 0;
    if (m0 + row < M) v = *(const bf16x8*)&Abf[(size_t)(m0 + row) * HD + seg];
    *(bf16x8*)&A_lds[row * HD + (seg ^ ((row & 7) << 3))] = v;
  }
  __syncthreads();

  // layer1 MFMA (K=128) -> h bf16 swizzled
  {
    bf16x8 Bf[2][4];
    #pragma unroll
    for (int nf = 0; nf < 2; nf++)
      #pragma unroll
      for (int ks = 0; ks < 4; ks++) {
        int col = wvid * 32 + nf * 16 + l15;
        Bf[nf][ks] = *(const bf16x8*)&w1t[(size_t)col * 128 + ks * 32 + l4 * 8];
      }
    f32x4 D[4][2];
    #pragma unroll
    for (int mi = 0; mi < 4; mi++)
      #pragma unroll
      for (int nf = 0; nf < 2; nf++)
        #pragma unroll
        for (int cc = 0; cc < 4; cc++) D[mi][nf][cc] = 0.f;

    #pragma unroll
    for (int mi = 0; mi < 4; mi++)
      #pragma unroll
      for (int ks = 0; ks < 4; ks++) {
        int row = mi * 16 + l15;
        bf16x8 Af = *(const bf16x8*)&A_lds[row * HD + ((ks * 32 + l4 * 8) ^ ((row & 7) << 3))];
        D[mi][0] = __builtin_amdgcn_mfma_f32_16x16x32_bf16(Af, Bf[0][ks], D[mi][0], 0, 0, 0);
        D[mi][1] = __builtin_amdgcn_mfma_f32_16x16x32_bf16(Af, Bf[1][ks], D[mi][1], 0, 0, 0);
      }

    float b1v0 = b1[wvid * 32 + l15];
    float b1v1 = b1[wvid * 32 + 16 + l15];
    #pragma unroll
    for (int mi = 0; mi < 4; mi++)
      #pragma unroll
      for (int nf = 0; nf < 2; nf++)
        #pragma unroll
        for (int r4 = 0; r4 < 4; r4++) {
          int row = mi * 16 + l4 * 4 + r4;
          int col = wvid * 32 + nf * 16 + l15;
          h_lds[row * HD + (col ^ ((row & 7) << 3))] =
              f2bf(prelu_f(D[mi][nf][r4] + (nf ? b1v1 : b1v0), a1));
        }
  }
  __syncthreads();

  // layer2 MFMA: 3 plane groups of 128 cols
  for (int m = 0; m < 3; m++) {
    bf16x8 Bf[2][4];
    #pragma unroll
    for (int nf = 0; nf < 2; nf++)
      #pragma unroll
      for (int ks = 0; ks < 4; ks++) {
        int col = m * 128 + wvid * 32 + nf * 16 + l15;
        Bf[nf][ks] = *(const bf16x8*)&w2t[(size_t)col * 128 + ks * 32 + l4 * 8];
      }
    f32x4 D[4][2];
    #pragma unroll
    for (int mi = 0; mi < 4; mi++)
      #pragma unroll
      for (int nf = 0; nf < 2; nf++)
        #pragma unroll
        for (int cc = 0; cc < 4; cc++) D[mi][nf][cc] = 0.f;

    #pragma unroll
    for (int mi = 0; mi < 4; mi++)
      #pragma unroll
      for (int ks = 0; ks < 4; ks++) {
        int row = mi * 16 + l15;
        bf16x8 Af = *(const bf16x8*)&h_lds[row * HD + ((ks * 32 + l4 * 8) ^ ((row & 7) << 3))];
        D[mi][0] = __builtin_amdgcn_mfma_f32_16x16x32_bf16(Af, Bf[0][ks], D[mi][0], 0, 0, 0);
        D[mi][1] = __builtin_amdgcn_mfma_f32_16x16x32_bf16(Af, Bf[1][ks], D[mi][1], 0, 0, 0);
      }

    float b2v0 = b2[m * 128 + wvid * 32 + l15];
    float b2v1 = b2[m * 128 + wvid * 32 + 16 + l15];
    #pragma unroll
    for (int mi = 0; mi < 4; mi++)
      #pragma unroll
      for (int nf = 0; nf < 2; nf++)
        #pragma unroll
        for (int r4 = 0; r4 < 4; r4++) {
          int row = mi * 16 + l4 * 4 + r4;
          if (m0 + row < M) {
            int col = m * 128 + wvid * 32 + nf * 16 + l15;
            out[(size_t)(m0 + row) * 384 + col] =
                f2bf(prelu_f(D[mi][nf][r4] + (nf ? b2v1 : b2v0), a2));
          }
        }
  }
}

// ---------------- CSR build (dual-branch fused) ----------------
__global__ __launch_bounds__(256) void zero_int_kernel(int* __restrict__ p, int n) {
  int i = blockIdx.x * 256 + threadIdx.x;
  if (i < n) p[i] = 0;
}

__global__ __launch_bounds__(256) void hist2_kernel(
    const int* __restrict__ edge_che, const int* __restrict__ edge_vdw,
    int* __restrict__ counts, int N, int E_che, int E_vdw)
{
  int g = blockIdx.x * 256 + threadIdx.x;
  if (g < E_che) {
    atomicAdd(&counts[edge_che[(size_t)g * 2]], 1);
  } else {
    int e2 = g - E_che;
    if (e2 < E_vdw) atomicAdd(&counts[N + edge_vdw[(size_t)e2 * 2]], 1);
  }
}

__global__ __launch_bounds__(256) void scan_partial2_kernel(
    const int* __restrict__ counts, int* __restrict__ partials, int n, int nb)
{
  const int b = blockIdx.x, t = threadIdx.x;
  const int br = b >= nb, lb = b - br * nb;
  const int* cnt = counts + (size_t)br * n;
  const int base = lb * SCAN_TILE + t * 8;
  int s = 0;
  #pragma unroll
  for (int i = 0; i < 8; i++) {
    int idx = base + i;
    if (idx < n) s += cnt[idx];
  }
  __shared__ int sums[256];
  sums[t] = s;
  __syncthreads();
  for (int o = 128; o > 0; o >>= 1) {
    if (t < o) sums[t] += sums[t + o];
    __syncthreads();
  }
  if (t == 0) partials[b] = sums[0];
}

__global__ __launch_bounds__(256) void scan_partials2_kernel(int* __restrict__ partials_g, int nb)
{
  int* partials = partials_g + blockIdx.x * nb;
  __shared__ int s[256];
  const int t = threadIdx.x;
  s[t] = (t < nb) ? partials[t] : 0;
  __syncthreads();
  for (int o = 1; o < 256; o <<= 1) {
    int v = s[t];
    int u = (t >= o) ? s[t - o] : 0;
    __syncthreads();
    s[t] = v + u;
    __syncthreads();
  }
  if (t < nb) partials[t] = (t == 0) ? 0 : s[t - 1];
}

__global__ __launch_bounds__(256) void scan_write2_kernel(
    const int* __restrict__ counts, const int* __restrict__ partials,
    int* __restrict__ offsets, int* __restrict__ cursor, int n, int nb,
    int E_che, int E_vdw)
{
  const int b = blockIdx.x, t = threadIdx.x;
  const int br = b >= nb, lb = b - br * nb;
  const int* cnt = counts + (size_t)br * n;
  int* offs = offsets + (size_t)br * (n + 1);
  int* curs = cursor + (size_t)br * n;
  const int base = lb * SCAN_TILE + t * 8;
  int vals[8];
  int s = 0;
  #pragma unroll
  for (int i = 0; i < 8; i++) {
    int idx = base + i;
    vals[i] = (idx < n) ? cnt[idx] : 0;
    s += vals[i];
  }
  __shared__ int sums[256];
  sums[t] = s;
  __syncthreads();
  for (int o = 1; o < 256; o <<= 1) {
    int v = sums[t];
    int u = (t >= o) ? sums[t - o] : 0;
    __syncthreads();
    sums[t] = v + u;
    __syncthreads();
  }
  int run = partials[b] + ((t == 0) ? 0 : sums[t - 1]);
  #pragma unroll
  for (int i = 0; i < 8; i++) {
    int idx = base + i;
    if (idx < n) {
      offs[idx] = run;
      curs[idx] = run;
      run += vals[i];
    }
  }
  if (lb == 0 && t == 0) offs[n] = br ? E_vdw : E_che;
}

__global__ __launch_bounds__(256) void scatter_ids2_kernel(
    const int* __restrict__ edge_che, const int* __restrict__ edge_vdw,
    int* __restrict__ cursor, int* __restrict__ edge_list,
    int N, int E_che, int E_vdw)
{
  int g = blockIdx.x * 256 + threadIdx.x;
  if (g < E_che) {
    int d = edge_che[(size_t)g * 2];
    int p = atomicAdd(&cursor[d], 1);
    edge_list[p] = g;
  } else {
    int e2 = g - E_che;
    if (e2 < E_vdw) {
      int d = edge_vdw[(size_t)e2 * 2];
      int p = atomicAdd(&cursor[N + d], 1);
      edge_list[E_che + p] = e2;
    }
  }
}

// permute edge data into CSR (dst-sorted) order, both branches, concatenated
__global__ __launch_bounds__(256) void permute2_kernel(
    const int* __restrict__ edge_list,
    const int* __restrict__ edge_che, const float* __restrict__ diff_che,
    const float* __restrict__ dist_che, const float* __restrict__ rbf_che,
    const int* __restrict__ edge_vdw, const float* __restrict__ diff_vdw,
    const float* __restrict__ dist_vdw, const float* __restrict__ rbf_vdw,
    int* __restrict__ src_s, int* __restrict__ dst_s,
    float4* __restrict__ unit_s, unsigned short* __restrict__ rbf_b,
    int E_che, int E_vdw)
{
  int p = blockIdx.x * 256 + threadIdx.x;
  if (p >= E_che + E_vdw) return;
  int br = p >= E_che;
  int e = edge_list[p];
  const int* edge = br ? edge_vdw : edge_che;
  const float* diff = br ? diff_vdw : diff_che;
  const float* dist = br ? dist_vdw : dist_che;
  const float* rbf  = br ? rbf_vdw  : rbf_che;
  src_s[p] = edge[(size_t)e * 2 + 1];
  dst_s[p] = edge[(size_t)e * 2 + 0];
  float inv = 1.f / dist[e];
  float4 u;
  u.x = diff[(size_t)e * 3 + 0] * inv;
  u.y = diff[(size_t)e * 3 + 1] * inv;
  u.z = diff[(size_t)e * 3 + 2] * inv;
  u.w = 0.f;
  unit_s[p] = u;
  ushort4* ro = (ushort4*)(rbf_b + (size_t)p * 32);
  const float* rr = &rbf[(size_t)e * 20];
  #pragma unroll
  for (int i = 0; i < 5; i++) {
    ushort4 o;
    o.x = f2bf(rr[4 * i + 0]); o.y = f2bf(rr[4 * i + 1]);
    o.z = f2bf(rr[4 * i + 2]); o.w = f2bf(rr[4 * i + 3]);
    ro[i] = o;
  }
  ushort4 z; z.x = 0; z.y = 0; z.z = 0; z.w = 0;
  ro[5] = z; ro[6] = z; ro[7] = z;
}

// ---------------- fused edge kernel (TILE=32): filter MLP (both layers MFMA) +
// bf16 gather + gate + in-LDS segmented reduction + direct RMW / boundary atomics ----------------
__global__ __launch_bounds__(256, 4) void edge_mfma_reduce_kernel(
    const unsigned short* __restrict__ so,  // [N,384] bf16
    const unsigned short* __restrict__ nv,  // [N,3,128] bf16
    const int*   __restrict__ src_s,   // [E] sorted
    const int*   __restrict__ dst_s,   // [E] sorted
    const float4* __restrict__ unit_s, // [E] sorted
    const unsigned short* __restrict__ rbf_b, // [E*32] sorted bf16 K-padded
    const int*   __restrict__ offsets, // [N+1] (branch's)
    const unsigned short* __restrict__ w1t, // [128][32] bf16
    const float* __restrict__ b1, const float* __restrict__ a1p,
    const unsigned short* __restrict__ w2t, // [384][128] bf16
    const float* __restrict__ b2, const float* __restrict__ a2p,
    float* __restrict__ out,           // [N,128]+[N,3,128] residual-initialized
    int N, int E)
{
  __shared__ __attribute__((aligned(16))) unsigned short A1_lds[TILE * 40]; // stride-40 pad
  __shared__ __attribute__((aligned(16))) unsigned short h_lds[TILE * HD];
  __shared__ __attribute__((aligned(16))) unsigned short P_lds[3][TILE * HD];
  __shared__ int src_l[TILE];
  __shared__ float unit_l[TILE][3];
  __shared__ int run_rs[TILE + 1], run_node[TILE], run_flag[TILE];
  __shared__ int nd_s;

  const int t = threadIdx.x;
  const int tx = t & 31, ty = t >> 5;
  const int c4 = tx * 4;
  const int wvid = t >> 6, lane = t & 63, l15 = lane & 15, l4 = lane >> 4;
  const int pblk = blockIdx.x * TILE;
  const int nrows = min(TILE, E - pblk);
  const float a1 = a1p[0], a2 = a2p[0];

  // wave0: meta staging + run detection (register-based, no LDS RAW)
  if (t < 64) {
    int d = -1, s = 0;
    float ux = 0.f, uy = 0.f, uz = 0.f;
    if (t < nrows) {
      s = src_s[pblk + t];
      d = dst_s[pblk + t];
      float4 u = unit_s[pblk + t];
      ux = u.x; uy = u.y; uz = u.z;
    }
    if (t < TILE) {
      src_l[t] = s;
      unit_l[t][0] = ux; unit_l[t][1] = uy; unit_l[t][2] = uz;
    }
    int dprev = __shfl_up(d, 1);
    bool flag = (t < nrows) && (t == 0 || d != dprev);
    unsigned long long mask = __ballot(flag ? 1 : 0);
    if (flag) {
      int j = __popcll(mask & ((1ull << t) - 1ull));
      run_rs[j] = t;
      run_node[j] = d;
      unsigned long long rest = (t == 63) ? 0ull : (mask >> (t + 1));
      int re = rest ? (t + 1 + (__ffsll((long long)rest) - 1)) : nrows;
      int interior = 1;
      if (t == 0 && offsets[d] != pblk) interior = 0;
      if (re == nrows && offsets[d + 1] != pblk + nrows) interior = 0;
      run_flag[j] = interior;
    }
    if (t == 0) {
      int nd = __popcll(mask);
      nd_s = nd;
      run_rs[nd] = nrows;
    }
  }

  // A1 staging: TILE rows x 32 bf16 (contiguous, coalesced), padded LDS stride 40
  if (t < TILE * 4) {
    const bf16x8* rb = (const bf16x8*)(rbf_b + (size_t)pblk * 32);
    int row = t >> 2, seg = (t & 3) * 8;
    *(bf16x8*)&A1_lds[row * 40 + seg] = rb[t];
  }
  __syncthreads();   // S1

  // layer1 MFMA (K=32) -> h bf16 swizzled
  {
    bf16x8 B1[2];
    B1[0] = *(const bf16x8*)&w1t[(size_t)(wvid * 32 + l15) * 32 + l4 * 8];
    B1[1] = *(const bf16x8*)&w1t[(size_t)(wvid * 32 + 16 + l15) * 32 + l4 * 8];
    f32x4 D1[2][2];
    #pragma unroll
    for (int mi = 0; mi < 2; mi++)
      #pragma unroll
      for (int nf = 0; nf < 2; nf++)
        #pragma unroll
        for (int cc = 0; cc < 4; cc++) D1[mi][nf][cc] = 0.f;

    #pragma unroll
    for (int mi = 0; mi < 2; mi++) {
      bf16x8 Af = *(const bf16x8*)&A1_lds[(mi * 16 + l15) * 40 + l4 * 8];
      D1[mi][0] = __builtin_amdgcn_mfma_f32_16x16x32_bf16(Af, B1[0], D1[mi][0], 0, 0, 0);
      D1[mi][1] = __builtin_amdgcn_mfma_f32_16x16x32_bf16(Af, B1[1], D1[mi][1], 0, 0, 0);
    }

    float b1v0 = b1[wvid * 32 + l15];
    float b1v1 = b1[wvid * 32 + 16 + l15];
    #pragma unroll
    for (int mi = 0; mi < 2; mi++)
      #pragma unroll
      for (int nf = 0; nf < 2; nf++)
        #pragma unroll
        for (int r4 = 0; r4 < 4; r4++) {
          int row = mi * 16 + l4 * 4 + r4;
          int col = wvid * 32 + nf * 16 + l15;
          h_lds[row * HD + (col ^ ((row & 7) << 3))] =
              f2bf(prelu_f(D1[mi][nf][r4] + (nf ? b1v1 : b1v0), a1));
        }
  }
  __syncthreads();   // S2

  // layer2 MFMA: 3 planes -> P_lds (gv, ms, ge gates)
  for (int m = 0; m < 3; m++) {
    bf16x8 Bf[2][4];
    #pragma unroll
    for (int nf = 0; nf < 2; nf++)
      #pragma unroll
      for (int ks = 0; ks < 4; ks++) {
        int col = m * 128 + wvid * 32 + nf * 16 + l15;
        Bf[nf][ks] = *(const bf16x8*)&w2t[(size_t)col * 128 + ks * 32 + l4 * 8];
      }
    f32x4 D[2][2];
    #pragma unroll
    for (int mi = 0; mi < 2; mi++)
      #pragma unroll
      for (int nf = 0; nf < 2; nf++)
        #pragma unroll
        for (int cc = 0; cc < 4; cc++) D[mi][nf][cc] = 0.f;

    #pragma unroll
    for (int mi = 0; mi < 2; mi++)
      #pragma unroll
      for (int ks = 0; ks < 4; ks++) {
        int row = mi * 16 + l15;
        bf16x8 Af = *(const bf16x8*)&h_lds[row * HD + ((ks * 32 + l4 * 8) ^ ((row & 7) << 3))];
        D[mi][0] = __builtin_amdgcn_mfma_f32_16x16x32_bf16(Af, Bf[0][ks], D[mi][0], 0, 0, 0);
        D[mi][1] = __builtin_amdgcn_mfma_f32_16x16x32_bf16(Af, Bf[1][ks], D[mi][1], 0, 0, 0);
      }

    float b2v0 = b2[m * 128 + wvid * 32 + l15];
    float b2v1 = b2[m * 128 + wvid * 32 + 16 + l15];
    #pragma unroll
    for (int mi = 0; mi < 2; mi++)
      #pragma unroll
      for (int nf = 0; nf < 2; nf++)
        #pragma unroll
        for (int r4 = 0; r4 < 4; r4++) {
          int row = mi * 16 + l4 * 4 + r4;
          int col = wvid * 32 + nf * 16 + l15;
          float v = prelu_f(D[mi][nf][r4] + (nf ? b2v1 : b2v0), a2);
          P_lds[m][row * HD + (col ^ ((row & 7) << 3))] = f2bf(v);
        }
  }
  __syncthreads();   // S3

  // epilogue A (owner phase): gather + gate; overwrite LDS planes in place with
  // final messages: ms -> h_lds, mv0/1/2 -> P_lds[0/1/2]. Per-cell exclusive.
  #pragma unroll
  for (int rr = 0; rr < 4; rr++) {
    const int r = ty * 4 + rr;
    const int src = src_l[r];
    const int sc = c4 ^ ((r & 7) << 3);
    f32x4 gvp = bf4_to_f32(*(const ushort4*)&P_lds[0][r * HD + sc]);
    f32x4 msp = bf4_to_f32(*(const ushort4*)&P_lds[1][r * HD + sc]);
    f32x4 gep = bf4_to_f32(*(const ushort4*)&P_lds[2][r * HD + sc]);
    const size_t sb = (size_t)src * 384;
    f32x4 s0 = bf4_to_f32(*(const ushort4*)&so[sb + c4]);
    f32x4 s1 = bf4_to_f32(*(const ushort4*)&so[sb + HD + c4]);
    f32x4 s2 = bf4_to_f32(*(const ushort4*)&so[sb + 2 * HD + c4]);
    f32x4 v0 = bf4_to_f32(*(const ushort4*)&nv[sb + c4]);
    f32x4 v1 = bf4_to_f32(*(const ushort4*)&nv[sb + HD + c4]);
    f32x4 v2 = bf4_to_f32(*(const ushort4*)&nv[sb + 2 * HD + c4]);
    const float u0 = unit_l[r][0], u1 = unit_l[r][1], u2 = unit_l[r][2];
    ushort4 msw, m0w, m1w, m2w;
    #pragma unroll
    for (int cc = 0; cc < 4; cc++) {
      float gv = gvp[cc] * s0[cc];
      float ms = msp[cc] * s1[cc];
      float ge = gep[cc] * s2[cc];
      float mv0 = v0[cc] * gv + u0 * ge;
      float mv1 = v1[cc] * gv + u1 * ge;
      float mv2 = v2[cc] * gv + u2 * ge;
      ((unsigned short*)&msw)[cc] = f2bf(ms);
      ((unsigned short*)&m0w)[cc] = f2bf(mv0);
      ((unsigned short*)&m1w)[cc] = f2bf(mv1);
      ((unsigned short*)&m2w)[cc] = f2bf(mv2);
    }
    *(ushort4*)&h_lds[r * HD + sc]    = msw;
    *(ushort4*)&P_lds[0][r * HD + sc] = m0w;
    *(ushort4*)&P_lds[1][r * HD + sc] = m1w;
    *(ushort4*)&P_lds[2][r * HD + sc] = m2w;
  }
  __syncthreads();   // S4

  // epilogue B (reduction phase): thread t owns 2 cols of one of 4 planes;
  // segment-sum over dst runs; interior -> plain f32x2 RMW, boundary -> atomics.
  {
    const int pl = t >> 6;            // 0: ms, 1..3: mv0..2
    const int c2 = (t & 63) * 2;
    const unsigned short* region = (pl == 0) ? h_lds : &P_lds[pl - 1][0];
    float* out_v = out + (size_t)N * HD;
    const int nd = nd_s;
    for (int j = 0; j < nd; j++) {
      const int rs = run_rs[j], re = run_rs[j + 1];
      const int n = run_node[j];
      float a0 = 0.f, a1v = 0.f;
      for (int r = rs; r < re; r++) {
        int ad = r * HD + (((c2 & ~3) ^ ((r & 7) << 3)) | (c2 & 3));
        unsigned int u = *(const unsigned int*)&region[ad];
        a0  += bf2f((unsigned short)(u & 0xffffu));
        a1v += bf2f((unsigned short)(u >> 16));
      }
      float* dstp = (pl == 0) ? (out + (size_t)n * HD + c2)
                              : (out_v + (size_t)n * 384 + (size_t)(pl - 1) * HD + c2);
      if (run_flag[j]) {
        float2 cur = *(float2*)dstp;
        cur.x += a0; cur.y += a1v;
        *(float2*)dstp = cur;
      } else {
        atomicAdd(dstp, a0);
        atomicAdd(dstp + 1, a1v);
      }
    }
  }
}

extern "C" void kernel_launch(void* const* d_in, const int* in_sizes, int n_in,
                              void* d_out, int out_size, void* d_ws, size_t ws_size,
                              hipStream_t stream)
{
  const float* node_scalar = (const float*)d_in[0];
  const float* node_vector = (const float*)d_in[1];
  const int*   che_edge = (const int*)d_in[2];
  const float* che_diff = (const float*)d_in[3];
  const float* che_dist = (const float*)d_in[4];
  const float* che_rbf  = (const float*)d_in[5];
  const int*   vdw_edge = (const int*)d_in[6];
  const float* vdw_diff = (const float*)d_in[7];
  const float* vdw_dist = (const float*)d_in[8];
  const float* vdw_rbf  = (const float*)d_in[9];
  const float* mlp_p[24];
  for (int i = 0; i < 24; i++) mlp_p[i] = (const float*)d_in[10 + i];
  // [che_s 0..5][che_f 6..11][vdw_s 12..17][vdw_f 18..23]

  const int N = in_sizes[0] / HD;
  const int E_che = in_sizes[4];
  const int E_vdw = in_sizes[8];
  const int E_sum = E_che + E_vdw;
  const int nb_scan = (N + SCAN_TILE - 1) / SCAN_TILE;

  // workspace layout
  char* wp = (char*)d_ws;
  size_t off = 0;
  unsigned short* so_bf = (unsigned short*)(wp + off); off += (size_t)N * 384 * 2;
  unsigned short* nv_bf = (unsigned short*)(wp + off); off += (size_t)N * 384 * 2;
  unsigned short* ns_bf = (unsigned short*)(wp + off); off += (size_t)N * 128 * 2;
  int* counts     = (int*)(wp + off);   off += (size_t)2 * N * 4;
  int* cursor     = (int*)(wp + off);   off += (size_t)2 * N * 4;
  int* offsets    = (int*)(wp + off);   off += (size_t)2 * (N + 1) * 4;
  int* partials   = (int*)(wp + off);   off += 512 * 4;
  off = (off + 255) & ~(size_t)255;
  int* edge_list  = (int*)(wp + off);   off += (size_t)E_sum * 4;
  int* src_s      = (int*)(wp + off);   off += (size_t)E_sum * 4;
  int* dst_s      = (int*)(wp + off);   off += (size_t)E_sum * 4;
  off = (off + 255) & ~(size_t)255;
  float4* unit_s  = (float4*)(wp + off); off += (size_t)E_sum * 16;
  unsigned short* rbf_b = (unsigned short*)(wp + off); off += (size_t)E_sum * 64;
  off = (off + 255) & ~(size_t)255;
  unsigned short* w2t_sche = (unsigned short*)(wp + off); off += 384 * 128 * 2;
  unsigned short* w2t_fche = (unsigned short*)(wp + off); off += 384 * 128 * 2;
  unsigned short* w2t_svdw = (unsigned short*)(wp + off); off += 384 * 128 * 2;
  unsigned short* w2t_fvdw = (unsigned short*)(wp + off); off += 384 * 128 * 2;
  unsigned short* w1t_nche = (unsigned short*)(wp + off); off += 128 * 128 * 2;
  unsigned short* w1t_nvdw = (unsigned short*)(wp + off); off += 128 * 128 * 2;
  unsigned short* w1t_eche = (unsigned short*)(wp + off); off += 128 * 32 * 2;
  unsigned short* w1t_evdw = (unsigned short*)(wp + off); off += 128 * 32 * 2;

  const int n_ns4 = N * HD / 4;
  const int n_nv4 = N * 3 * HD / 4;
  init_conv_kernel<<<2048, 256, 0, stream>>>(
      (const f32x4*)node_scalar, (const f32x4*)node_vector, (f32x4*)d_out,
      (ushort4*)ns_bf, (ushort4*)nv_bf, n_ns4, n_nv4);

  weights_prep_kernel<<<928, 256, 0, stream>>>(
      mlp_p[3], mlp_p[9], mlp_p[15], mlp_p[21],
      mlp_p[0], mlp_p[12], mlp_p[6], mlp_p[18],
      w2t_sche, w2t_fche, w2t_svdw, w2t_fvdw,
      w1t_nche, w1t_nvdw, w1t_eche, w1t_evdw);

  // dual-branch CSR build
  zero_int_kernel<<<(2 * N + 255) / 256, 256, 0, stream>>>(counts, 2 * N);
  hist2_kernel<<<(E_sum + 255) / 256, 256, 0, stream>>>(
      che_edge, vdw_edge, counts, N, E_che, E_vdw);
  scan_partial2_kernel<<<2 * nb_scan, 256, 0, stream>>>(counts, partials, N, nb_scan);
  scan_partials2_kernel<<<2, 256, 0, stream>>>(partials, nb_scan);
  scan_write2_kernel<<<2 * nb_scan, 256, 0, stream>>>(
      counts, partials, offsets, cursor, N, nb_scan, E_che, E_vdw);
  scatter_ids2_kernel<<<(E_sum + 255) / 256, 256, 0, stream>>>(
      che_edge, vdw_edge, cursor, edge_list, N, E_che, E_vdw);
  permute2_kernel<<<(E_sum + 255) / 256, 256, 0, stream>>>(
      edge_list,
      che_edge, che_diff, che_dist, che_rbf,
      vdw_edge, vdw_diff, vdw_dist, vdw_rbf,
      src_s, dst_s, unit_s, rbf_b, E_che, E_vdw);

  for (int br = 0; br < 2; br++) {
    const int E = br == 0 ? E_che : E_vdw;
    const int base = br == 0 ? 0 : E_che;
    const float* const* sp = &mlp_p[br == 0 ? 0 : 12];
    const float* const* fp = &mlp_p[br == 0 ? 6 : 18];
    const unsigned short* w2t_s = br == 0 ? w2t_sche : w2t_svdw;
    const unsigned short* w2t_f = br == 0 ? w2t_fche : w2t_fvdw;
    const unsigned short* w1t_n = br == 0 ? w1t_nche : w1t_nvdw;
    const unsigned short* w1t_e = br == 0 ? w1t_eche : w1t_evdw;

    node_mlp_mfma<<<(N + 63) / 64, 256, 0, stream>>>(
        ns_bf, w1t_n, sp[1], sp[2], w2t_s, sp[4], sp[5], so_bf, N);

    edge_mfma_reduce_kernel<<<(E + TILE - 1) / TILE, 256, 0, stream>>>(
        so_bf, nv_bf,
        src_s + base, dst_s + base, unit_s + base, rbf_b + (size_t)base * 32,
        offsets + (size_t)br * (N + 1),
        w1t_e, fp[1], fp[2], w2t_f, fp[4], fp[5],
        (float*)d_out, N, E);
  }
}